// Round 5
// baseline (749.638 us; speedup 1.0000x reference)
//
#include <hip/hip_runtime.h>
#include <math.h>
#include <stdint.h>

#define B_ 4
#define C_ 256
#define H_ 128
#define W_ 128
#define NPIX (H_*W_)

typedef short bf16x8 __attribute__((ext_vector_type(8)));
typedef int   i32x4  __attribute__((ext_vector_type(4)));
typedef float f32x16 __attribute__((ext_vector_type(16)));
typedef unsigned short u16x4 __attribute__((ext_vector_type(4)));

// ---- LDS map ----
#define XSZ   41984              // 328 slots * 128 B (one 64-c quarter of 18x18 halo)
#define WOFF  (2*XSZ)            // 83968
#define WSL   32768              // one W slice: 256 o * 64 c * 2 B
#define SCR   (WOFF + 2*WSL)     // 149504: 1 KB scratch for dummy stage ops
#define LDS_TOTAL (SCR + 1024)   // 150528 <= 163840

__device__ __forceinline__ unsigned short f2bf_rne(float v) {
    uint32_t b = __float_as_uint(v);
    return (unsigned short)((b + 0x7fff + ((b >> 16) & 1)) >> 16);
}
__device__ __forceinline__ float bf2f(unsigned short h) {
    return __uint_as_float(((uint32_t)h) << 16);
}

// ---- prep: 36 W slices, slice sl = qt*9 + k; image[o][u'][e] with u' = u ^ (o&7),
//      c = qt*64 + u*8 + e.  Block 2304 zeroes the zero block.
__global__ __launch_bounds__(256)
void prep_w(const float* __restrict__ wg, unsigned short* __restrict__ wb,
            unsigned short* __restrict__ zb) {
    if (blockIdx.x == 2304) { if (threadIdx.x < 128) zb[threadIdx.x] = 0; return; }
    int f = blockIdx.x * 256 + threadIdx.x;          // < 589824
    int sl = f >> 14, within = f & 16383;
    int o = within >> 6, t = within & 63;
    int up = t >> 3, e = t & 7;
    int qt = sl / 9, k = sl - qt * 9;
    int c = qt * 64 + ((up ^ (o & 7)) << 3) + e;
    wb[f] = f2bf_rne(wg[(o * C_ + c) * 9 + k]);
}

// ---- prep: retina fp32 (B,C,H,W) -> channel-last hi/lo bf16 shadows (B,H,W,C)
__global__ __launch_bounds__(256)
void prep_split(const float* __restrict__ retina, unsigned short* __restrict__ hi,
                unsigned short* __restrict__ lo) {
    __shared__ unsigned int t[64][65];
    int bid = blockIdx.x;
    const int wt = bid & 1;        bid >>= 1;
    const int h  = bid & 127;      bid >>= 7;
    const int ct = bid & 3;        const int b = bid >> 2;
    const int tid = threadIdx.x;
    const int ci4 = tid >> 6, wi = tid & 63;
    #pragma unroll
    for (int cc = 0; cc < 16; ++cc) {
        int c_loc = cc * 4 + ci4;
        float v = retina[((size_t)(b * C_ + ct * 64 + c_loc) * H_ + h) * W_ + wt * 64 + wi];
        unsigned short hv = f2bf_rne(v);
        unsigned short lv = f2bf_rne(v - bf2f(hv));
        t[c_loc][wi] = (unsigned)hv | ((unsigned)lv << 16);
    }
    __syncthreads();
    const int p = tid >> 2, j = tid & 3;
    size_t base = (((size_t)(b * H_ + h) * W_ + wt * 64 + p) << 8) + ct * 64 + j * 16;
    u16x4 hv4[4], lv4[4];
    #pragma unroll
    for (int e = 0; e < 16; ++e) {
        unsigned u = t[j * 16 + e][p];
        hv4[e >> 2][e & 3] = (unsigned short)(u & 0xffffu);
        lv4[e >> 2][e & 3] = (unsigned short)(u >> 16);
    }
    #pragma unroll
    for (int q2 = 0; q2 < 4; ++q2) {
        *(u16x4*)(hi + base + q2 * 4) = hv4[q2];
        *(u16x4*)(lo + base + q2 * 4) = lv4[q2];
    }
}

// ---- staging: per-wave uniform op counts (W slice = 4 glds/wave, x quarter = 6)
__device__ __forceinline__ void stage_w(const unsigned short* __restrict__ wb_all,
                                        char* smem, int woff, int sl, int wid, int l) {
    const char* src = (const char*)wb_all + ((size_t)sl << 15);
    #pragma unroll
    for (int j = 0; j < 4; ++j) {
        const int seg = ((j << 3) + wid) << 10;      // (j*8 + wid) * 1024
        __builtin_amdgcn_global_load_lds(
            (const __attribute__((address_space(1))) uint32_t*)(src + seg + l * 16),
            (__attribute__((address_space(3))) uint32_t*)(smem + woff + seg), 16, 0, 0);
    }
    __builtin_amdgcn_sched_barrier(0);
}

__device__ __forceinline__ void stage_x(const unsigned short* __restrict__ hi_in,
                                        const unsigned short* __restrict__ zb,
                                        char* smem, int xoff, int b, int tr, int tc,
                                        int qt, int wid, int l) {
    const int slot_r = l >> 3, sub = l & 7;
    #pragma unroll
    for (int op = 0; op < 6; ++op) {
        const int sbase = (op << 6) + (wid << 3);    // 0..383, wave-uniform
        const int s = sbase + slot_r;
        const int rr = (s * 3641) >> 16;             // s/18 for s<=383
        const int hc = s - rr * 18;
        const int h = tr * 16 + rr - 1;
        const int w = tc * 16 + hc - 1;
        const unsigned short* src;
        int dst;
        if (sbase < 328) {                           // valid op (uniform)
            dst = xoff + (sbase << 7);
            if ((unsigned)h < 128u && (unsigned)w < 128u)
                src = hi_in + ((((size_t)(b * 128 + h) << 7) + w) << 8) + (qt << 6)
                            + ((sub ^ (s & 7)) << 3);  // swizzle folded into global addr
            else
                src = zb + (sub << 3);               // zero halo
        } else {                                     // dummy op: keep vmcnt uniform
            dst = SCR;
            src = zb + (sub << 3);
        }
        __builtin_amdgcn_global_load_lds(
            (const __attribute__((address_space(1))) uint32_t*)src,
            (__attribute__((address_space(3))) uint32_t*)(smem + dst), 16, 0, 0);
    }
    __builtin_amdgcn_sched_barrier(0);
}

// ---- main step: 8 waves, 32x32x16 MFMA, 4x2 frags/wave, counted-vmcnt pipeline
__global__ __launch_bounds__(512, 2)
void nca_v6(const unsigned short* __restrict__ hi_in,
            const unsigned short* __restrict__ lo_in,
            const unsigned short* __restrict__ wb,
            const unsigned short* __restrict__ zb,
            const float* __restrict__ mask,
            unsigned short* __restrict__ hi_out,
            unsigned short* __restrict__ lo_out,
            float* __restrict__ out_f32,
            int final_step)
{
    extern __shared__ char smem[];
    const int tid = threadIdx.x;
    const int l = tid & 63, wid = tid >> 6;          // 8 waves
    const int wave_o = wid & 1, wave_p = wid >> 1;   // o-halves x 4 row-groups
    const int lane31 = l & 31, khalf = l >> 5;
    const int col = l & 15, rowin = (l >> 4) & 1;

    int bid = blockIdx.x;
    const int tc = bid & 7; bid >>= 3;
    const int tr = bid & 7; const int b = bid >> 3;

    // mask bits first (consumed immediately so vmcnt counting below stays exact)
    unsigned mbits = 0;
    #pragma unroll
    for (int k = 0; k < 9; ++k) {
        #pragma unroll
        for (int n = 0; n < 2; ++n) {
            const int h = tr * 16 + wave_p * 4 + n * 2 + rowin;
            const int w = tc * 16 + col;
            unsigned bit = (mask[k * NPIX + h * W_ + w] != 0.f) ? 1u : 0u;
            mbits |= bit << (k * 2 + n);
        }
    }
    __builtin_amdgcn_sched_barrier(0);

    // prologue queue (per wave): W0(4) W1(4) X0(6) X1(6)
    stage_w(wb, smem, WOFF,       0, wid, l);
    stage_w(wb, smem, WOFF + WSL, 1, wid, l);
    stage_x(hi_in, zb, smem, 0,   b, tr, tc, 0, wid, l);
    stage_x(hi_in, zb, smem, XSZ, b, tr, tc, 1, wid, l);

    int sB[2];
    #pragma unroll
    for (int n = 0; n < 2; ++n) sB[n] = (wave_p * 4 + n * 2 + rowin) * 18 + col;
    int abase[4], aswz[4];
    #pragma unroll
    for (int mo = 0; mo < 4; ++mo) {
        int o_l = wave_o * 128 + mo * 32 + lane31;
        abase[mo] = o_l << 7;
        aswz[mo] = o_l & 7;
    }

    f32x16 zv;
    #pragma unroll
    for (int r = 0; r < 16; ++r) zv[r] = 0.f;
    f32x16 acc[4][2];
    #pragma unroll
    for (int mo = 0; mo < 4; ++mo)
        #pragma unroll
        for (int n = 0; n < 2; ++n) acc[mo][n] = zv;

    #pragma unroll 1
    for (int qt = 0; qt < 4; ++qt) {
        const char* xbuf = smem + ((qt & 1) ? XSZ : 0);
        #pragma unroll 1
        for (int k = 0; k < 9; ++k) {
            const int sl = qt * 9 + k;
            // per-wave counted waits (W=4 ops, X=6 ops):
            //  (0,k<=1): drain X0 -> vmcnt(6); (qt 1|2, k<=1): drain W[sl]+X[qt] -> vmcnt(10)
            //  steady: vmcnt(4) keeps W[sl+1] in flight; sl==35: vmcnt(0)
            if (qt == 0 && k <= 1)                 asm volatile("s_waitcnt vmcnt(6)"  ::: "memory");
            else if ((qt == 1 || qt == 2) && k <= 1) asm volatile("s_waitcnt vmcnt(10)" ::: "memory");
            else if (sl == 35)                     asm volatile("s_waitcnt vmcnt(0)"  ::: "memory");
            else                                   asm volatile("s_waitcnt vmcnt(4)"  ::: "memory");
            __builtin_amdgcn_sched_barrier(0);
            __builtin_amdgcn_s_barrier();

            const int dy = (k * 11) >> 5;
            const int dx = k - dy * 3;
            const int doff = dy * 18 + dx;
            const char* wbuf = smem + WOFF + ((sl & 1) ? WSL : 0);
            const unsigned mk = mbits >> (k * 2);

            int sx[2];
            #pragma unroll
            for (int n = 0; n < 2; ++n) sx[n] = sB[n] + doff;

            __builtin_amdgcn_s_setprio(1);
            #pragma unroll
            for (int ks = 0; ks < 4; ++ks) {
                const int ua = ks * 2 + khalf;
                bf16x8 av[4];
                #pragma unroll
                for (int mo = 0; mo < 4; ++mo)
                    av[mo] = *(const bf16x8*)(wbuf + abase[mo] + ((ua ^ aswz[mo]) << 4));
                bf16x8 bv[2];
                #pragma unroll
                for (int n = 0; n < 2; ++n) {
                    i32x4 braw = *(const i32x4*)(xbuf + sx[n] * 128 + ((ua ^ (sx[n] & 7)) << 4));
                    const int mm = -(int)((mk >> n) & 1u);
                    #pragma unroll
                    for (int w4 = 0; w4 < 4; ++w4) braw[w4] &= mm;   // binary mask, exact
                    bv[n] = __builtin_bit_cast(bf16x8, braw);
                }
                #pragma unroll
                for (int mo = 0; mo < 4; ++mo)
                    #pragma unroll
                    for (int n = 0; n < 2; ++n)
                        acc[mo][n] = __builtin_amdgcn_mfma_f32_32x32x16_bf16(av[mo], bv[n], acc[mo][n], 0, 0, 0);
            }
            __builtin_amdgcn_s_setprio(0);

            asm volatile("" ::: "memory");
            __builtin_amdgcn_s_barrier();
            if (sl + 2 < 36)
                stage_w(wb, smem, WOFF + ((sl & 1) ? WSL : 0), sl + 2, wid, l);
            if (k == 8 && qt < 2)
                stage_x(hi_in, zb, smem, (qt & 1) ? XSZ : 0, b, tr, tc, qt + 2, wid, l);
        }
    }

    // ---- epilogue: residual + squash; write hi/lo shadows (or fp32 on final step)
    #pragma unroll
    for (int mo = 0; mo < 4; ++mo) {
        #pragma unroll
        for (int n = 0; n < 2; ++n) {
            const int h = tr * 16 + wave_p * 4 + n * 2 + rowin;
            const int w = tc * 16 + col;
            const size_t pixidx = ((size_t)((b * 128 + h) * 128 + w)) << 8;
            #pragma unroll
            for (int rq = 0; rq < 4; ++rq) {
                const int o0 = wave_o * 128 + mo * 32 + rq * 8 + khalf * 4;
                u16x4 h4 = *(const u16x4*)(hi_in + pixidx + o0);
                u16x4 l4 = *(const u16x4*)(lo_in + pixidx + o0);
                float xn[4];
                #pragma unroll
                for (int r = 0; r < 4; ++r) {
                    float xv = bf2f(h4[r]) + bf2f(l4[r]);
                    float d = acc[mo][n][rq * 4 + r];
                    xn[r] = xv + d / (1.f + fabsf(d));
                }
                if (final_step) {
                    #pragma unroll
                    for (int r = 0; r < 4; ++r)
                        out_f32[((size_t)(b * C_ + o0 + r) * H_ + h) * W_ + w] = xn[r];
                } else {
                    u16x4 ho, lo;
                    #pragma unroll
                    for (int r = 0; r < 4; ++r) {
                        ho[r] = f2bf_rne(xn[r]);
                        lo[r] = f2bf_rne(xn[r] - bf2f(ho[r]));
                    }
                    *(u16x4*)(hi_out + pixidx + o0) = ho;
                    *(u16x4*)(lo_out + pixidx + o0) = lo;
                }
            }
        }
    }
}

// ================= fp32 fallback (only if ws too small) =================
#define OT 64
#define TR 4
#define TC 16
#define CKC 16
__global__ __launch_bounds__(256)
void nca_step_f32(const float* __restrict__ xin, const float* __restrict__ wg,
                  const float* __restrict__ mask, float* __restrict__ xout)
{
    __shared__ __align__(16) float w_s[CKC][9][OT];
    __shared__ __align__(16) float x_s[CKC][TR + 2][20];
    const int tid = threadIdx.x;
    int bt = blockIdx.x;
    const int col_tile = bt & 7;  bt >>= 3;
    const int row_tile = bt & 31; bt >>= 5;
    const int ot = bt & 3;        const int b = bt >> 2;
    const int gr0 = row_tile * TR, gc0 = col_tile * TC, o_base = ot * OT;
    const int og = tid >> 4, pg = tid & 15;
    const int prow = pg >> 2, pcol4 = (pg & 3) * 4;
    const int orow = gr0 + prow, ocol0 = gc0 + pcol4;
    float mask_r[9][4];
#pragma unroll
    for (int k = 0; k < 9; ++k)
#pragma unroll
        for (int j = 0; j < 4; ++j)
            mask_r[k][j] = mask[k * NPIX + orow * W_ + (ocol0 + j)];
    float acc[4][4];
#pragma unroll
    for (int a = 0; a < 4; ++a)
#pragma unroll
        for (int j = 0; j < 4; ++j) acc[a][j] = 0.f;
    for (int chunk = 0; chunk < C_ / CKC; ++chunk) {
        const int c0 = chunk * CKC;
#pragma unroll
        for (int i = 0; i < 36; ++i) {
            const int flat = i * 256 + tid;
            const int o_l = flat / 144;
            const int r = flat - o_l * 144;
            const int c_l = r / 9;
            const int kk = r - c_l * 9;
            w_s[c_l][kk][o_l] = wg[(o_base + o_l) * (C_ * 9) + (c0 + c_l) * 9 + kk];
        }
#pragma unroll
        for (int i = 0; i < 7; ++i) {
            const int flat = i * 256 + tid;
            if (flat < CKC * 108) {
                const int c_l = flat / 108;
                const int r = flat - c_l * 108;
                const int row = r / 18, colx = r - row * 18;
                const int grow = gr0 - 1 + row, gcol = gc0 - 1 + colx;
                float v = 0.f;
                if ((unsigned)grow < (unsigned)H_ && (unsigned)gcol < (unsigned)W_)
                    v = xin[((b * C_ + c0 + c_l) * H_ + grow) * W_ + gcol];
                x_s[c_l][row][colx] = v;
            }
        }
        __syncthreads();
#pragma unroll
        for (int dyy = 0; dyy < 3; ++dyy) {
            float acck[3][4][4];
#pragma unroll
            for (int dxx = 0; dxx < 3; ++dxx)
#pragma unroll
                for (int a = 0; a < 4; ++a)
#pragma unroll
                    for (int j = 0; j < 4; ++j) acck[dxx][a][j] = 0.f;
#pragma unroll 4
            for (int c = 0; c < CKC; ++c) {
                const float4 xv4 = *(const float4*)&x_s[c][prow + dyy][pcol4];
                const float2 xv2 = *(const float2*)&x_s[c][prow + dyy][pcol4 + 4];
                const float xv[6] = {xv4.x, xv4.y, xv4.z, xv4.w, xv2.x, xv2.y};
#pragma unroll
                for (int dxx = 0; dxx < 3; ++dxx) {
                    const float4 wv = *(const float4*)&w_s[c][dyy * 3 + dxx][og * 4];
                    const float wa[4] = {wv.x, wv.y, wv.z, wv.w};
#pragma unroll
                    for (int a = 0; a < 4; ++a)
#pragma unroll
                        for (int j = 0; j < 4; ++j)
                            acck[dxx][a][j] = fmaf(wa[a], xv[j + dxx], acck[dxx][a][j]);
                }
            }
#pragma unroll
            for (int dxx = 0; dxx < 3; ++dxx) {
                const int k = dyy * 3 + dxx;
#pragma unroll
                for (int a = 0; a < 4; ++a)
#pragma unroll
                    for (int j = 0; j < 4; ++j)
                        acc[a][j] = fmaf(mask_r[k][j], acck[dxx][a][j], acc[a][j]);
            }
        }
        __syncthreads();
    }
#pragma unroll
    for (int a = 0; a < 4; ++a) {
        const int o = o_base + og * 4 + a;
#pragma unroll
        for (int j = 0; j < 4; ++j) {
            const int idx = ((b * C_ + o) * H_ + orow) * W_ + (ocol0 + j);
            const float d = acc[a][j];
            xout[idx] = xin[idx] + d / (1.0f + fabsf(d));
        }
    }
}

extern "C" void kernel_launch(void* const* d_in, const int* in_sizes, int n_in,
                              void* d_out, int out_size, void* d_ws, size_t ws_size,
                              hipStream_t stream) {
    const float* retina = (const float*)d_in[0];
    const float* wg     = (const float*)d_in[1];
    const float* mask   = (const float*)d_in[2];
    float* out = (float*)d_out;

    const size_t need = 0x6200000;   // wb+zb (2M) + hiA/loA/loB (3x32M)

    if (ws_size >= need) {
        unsigned short* wb  = (unsigned short*)d_ws;
        unsigned short* zb  = (unsigned short*)((char*)d_ws + 0x120000);
        unsigned short* hiA = (unsigned short*)((char*)d_ws + 0x200000);
        unsigned short* loA = (unsigned short*)((char*)d_ws + 0x2200000);
        unsigned short* loB = (unsigned short*)((char*)d_ws + 0x4200000);
        unsigned short* hiB = (unsigned short*)d_out;   // scratch through step 4

        hipFuncSetAttribute((const void*)nca_v6,
                            hipFuncAttributeMaxDynamicSharedMemorySize, LDS_TOTAL);

        prep_w<<<2305, 256, 0, stream>>>(wg, wb, zb);
        prep_split<<<4096, 256, 0, stream>>>(retina, hiA, loA);

        nca_v6<<<256, 512, LDS_TOTAL, stream>>>(hiA, loA, wb, zb, mask, hiB, loB, out, 0);
        nca_v6<<<256, 512, LDS_TOTAL, stream>>>(hiB, loB, wb, zb, mask, hiA, loA, out, 0);
        nca_v6<<<256, 512, LDS_TOTAL, stream>>>(hiA, loA, wb, zb, mask, hiB, loB, out, 0);
        nca_v6<<<256, 512, LDS_TOTAL, stream>>>(hiB, loB, wb, zb, mask, hiA, loA, out, 0);
        nca_v6<<<256, 512, LDS_TOTAL, stream>>>(hiA, loA, wb, zb, mask, hiA, loA, out, 1);
    } else {
        float* ws = (float*)d_ws;
        const int nblocks = B_ * (C_ / OT) * (H_ / TR) * (W_ / TC);
        const float* src = retina;
        float* dsts[5] = {out, ws, out, ws, out};
        for (int s = 0; s < 5; ++s) {
            nca_step_f32<<<dim3(nblocks), dim3(256), 0, stream>>>(src, wg, mask, dsts[s]);
            src = dsts[s];
        }
    }
}

// Round 6
// 484.421 us; speedup vs baseline: 1.5475x; 1.5475x over previous
//
#include <hip/hip_runtime.h>
#include <math.h>
#include <stdint.h>

#define B_ 4
#define C_ 256
#define H_ 128
#define W_ 128
#define NPIX (H_*W_)

typedef short bf16x8 __attribute__((ext_vector_type(8)));
typedef int   i32x4  __attribute__((ext_vector_type(4)));
typedef float f32x4  __attribute__((ext_vector_type(4)));
typedef float f32x16 __attribute__((ext_vector_type(16)));
typedef unsigned short u16x4 __attribute__((ext_vector_type(4)));

// ---- LDS map ----
#define XSZ   41984              // 328 slots * 128 B (one 64-c quarter of 18x18 halo)
#define WOFF  (2*XSZ)            // 83968
#define WSL   32768              // one W slice: 256 o * 64 c * 2 B
#define SCR   (WOFF + 2*WSL)     // 149504: 1 KB scratch for dummy stage ops
#define LDS_TOTAL (SCR + 1024)   // 150528 <= 163840 (epilogue reuses first 128 KB)

__device__ __forceinline__ unsigned short f2bf_rne(float v) {
    uint32_t b = __float_as_uint(v);
    return (unsigned short)((b + 0x7fff + ((b >> 16) & 1)) >> 16);
}
__device__ __forceinline__ float bf2f(unsigned short h) {
    return __uint_as_float(((uint32_t)h) << 16);
}

// ---- prep: 36 W slices, slice sl = qt*9 + k; image[o][u'][e] with u' = u ^ (o&7),
//      c = qt*64 + u*8 + e.  Block 2304 zeroes the zero block.
__global__ __launch_bounds__(256)
void prep_w(const float* __restrict__ wg, unsigned short* __restrict__ wb,
            unsigned short* __restrict__ zb) {
    if (blockIdx.x == 2304) { if (threadIdx.x < 128) zb[threadIdx.x] = 0; return; }
    int f = blockIdx.x * 256 + threadIdx.x;          // < 589824
    int sl = f >> 14, within = f & 16383;
    int o = within >> 6, t = within & 63;
    int up = t >> 3, e = t & 7;
    int qt = sl / 9, k = sl - qt * 9;
    int c = qt * 64 + ((up ^ (o & 7)) << 3) + e;
    wb[f] = f2bf_rne(wg[(o * C_ + c) * 9 + k]);
}

// ---- prep: retina fp32 (B,C,H,W) -> channel-last hi/lo bf16 shadows (B,H,W,C)
__global__ __launch_bounds__(256)
void prep_split(const float* __restrict__ retina, unsigned short* __restrict__ hi,
                unsigned short* __restrict__ lo) {
    __shared__ unsigned int t[64][65];
    int bid = blockIdx.x;
    const int wt = bid & 1;        bid >>= 1;
    const int h  = bid & 127;      bid >>= 7;
    const int ct = bid & 3;        const int b = bid >> 2;
    const int tid = threadIdx.x;
    const int ci4 = tid >> 6, wi = tid & 63;
    #pragma unroll
    for (int cc = 0; cc < 16; ++cc) {
        int c_loc = cc * 4 + ci4;
        float v = retina[((size_t)(b * C_ + ct * 64 + c_loc) * H_ + h) * W_ + wt * 64 + wi];
        unsigned short hv = f2bf_rne(v);
        unsigned short lv = f2bf_rne(v - bf2f(hv));
        t[c_loc][wi] = (unsigned)hv | ((unsigned)lv << 16);
    }
    __syncthreads();
    const int p = tid >> 2, j = tid & 3;
    size_t base = (((size_t)(b * H_ + h) * W_ + wt * 64 + p) << 8) + ct * 64 + j * 16;
    u16x4 hv4[4], lv4[4];
    #pragma unroll
    for (int e = 0; e < 16; ++e) {
        unsigned u = t[j * 16 + e][p];
        hv4[e >> 2][e & 3] = (unsigned short)(u & 0xffffu);
        lv4[e >> 2][e & 3] = (unsigned short)(u >> 16);
    }
    #pragma unroll
    for (int q2 = 0; q2 < 4; ++q2) {
        *(u16x4*)(hi + base + q2 * 4) = hv4[q2];
        *(u16x4*)(lo + base + q2 * 4) = lv4[q2];
    }
}

// ---- staging: per-wave uniform op counts (W slice = 4 glds/wave, x quarter = 6)
__device__ __forceinline__ void stage_w(const unsigned short* __restrict__ wb_all,
                                        char* smem, int woff, int sl, int wid, int l) {
    const char* src = (const char*)wb_all + ((size_t)sl << 15);
    #pragma unroll
    for (int j = 0; j < 4; ++j) {
        const int seg = ((j << 3) + wid) << 10;      // (j*8 + wid) * 1024
        __builtin_amdgcn_global_load_lds(
            (const __attribute__((address_space(1))) uint32_t*)(src + seg + l * 16),
            (__attribute__((address_space(3))) uint32_t*)(smem + woff + seg), 16, 0, 0);
    }
    __builtin_amdgcn_sched_barrier(0);
}

__device__ __forceinline__ void stage_x(const unsigned short* __restrict__ hi_in,
                                        const unsigned short* __restrict__ zb,
                                        char* smem, int xoff, int b, int tr, int tc,
                                        int qt, int wid, int l) {
    const int slot_r = l >> 3, sub = l & 7;
    #pragma unroll
    for (int op = 0; op < 6; ++op) {
        const int sbase = (op << 6) + (wid << 3);    // 0..383, wave-uniform
        const int s = sbase + slot_r;
        const int rr = (s * 3641) >> 16;             // s/18 for s<=383
        const int hc = s - rr * 18;
        const int h = tr * 16 + rr - 1;
        const int w = tc * 16 + hc - 1;
        const unsigned short* src;
        int dst;
        if (sbase < 328) {                           // valid op (uniform)
            dst = xoff + (sbase << 7);
            if ((unsigned)h < 128u && (unsigned)w < 128u)
                src = hi_in + ((((size_t)(b * 128 + h) << 7) + w) << 8) + (qt << 6)
                            + ((sub ^ (s & 7)) << 3);  // swizzle folded into global addr
            else
                src = zb + (sub << 3);               // zero halo
        } else {                                     // dummy op: keep vmcnt uniform
            dst = SCR;
            src = zb + (sub << 3);
        }
        __builtin_amdgcn_global_load_lds(
            (const __attribute__((address_space(1))) uint32_t*)src,
            (__attribute__((address_space(3))) uint32_t*)(smem + dst), 16, 0, 0);
    }
    __builtin_amdgcn_sched_barrier(0);
}

// ---- main step: 8 waves, 32x32x16 MFMA, 4x2 frags/wave, counted-vmcnt pipeline,
//      LDS-transpose epilogue for fully-coalesced hi/lo read-modify-write
__global__ __launch_bounds__(512, 2)
void nca_v7(const unsigned short* __restrict__ hi_in,
            const unsigned short* __restrict__ lo_in,
            const unsigned short* __restrict__ wb,
            const unsigned short* __restrict__ zb,
            const float* __restrict__ mask,
            unsigned short* __restrict__ hi_out,
            unsigned short* __restrict__ lo_out)
{
    extern __shared__ char smem[];
    const int tid = threadIdx.x;
    const int l = tid & 63, wid = tid >> 6;          // 8 waves
    const int wave_o = wid & 1, wave_p = wid >> 1;   // o-halves x 4 row-groups
    const int lane31 = l & 31, khalf = l >> 5;
    const int col = l & 15, rowin = (l >> 4) & 1;

    int bid = blockIdx.x;
    const int tc = bid & 7; bid >>= 3;
    const int tr = bid & 7; const int b = bid >> 3;

    // mask bits first (consumed immediately so vmcnt counting below stays exact)
    unsigned mbits = 0;
    #pragma unroll
    for (int k = 0; k < 9; ++k) {
        #pragma unroll
        for (int n = 0; n < 2; ++n) {
            const int h = tr * 16 + wave_p * 4 + n * 2 + rowin;
            const int w = tc * 16 + col;
            unsigned bit = (mask[k * NPIX + h * W_ + w] != 0.f) ? 1u : 0u;
            mbits |= bit << (k * 2 + n);
        }
    }
    __builtin_amdgcn_sched_barrier(0);

    // prologue queue (per wave): W0(4) W1(4) X0(6) X1(6)
    stage_w(wb, smem, WOFF,       0, wid, l);
    stage_w(wb, smem, WOFF + WSL, 1, wid, l);
    stage_x(hi_in, zb, smem, 0,   b, tr, tc, 0, wid, l);
    stage_x(hi_in, zb, smem, XSZ, b, tr, tc, 1, wid, l);

    int sB[2];
    #pragma unroll
    for (int n = 0; n < 2; ++n) sB[n] = (wave_p * 4 + n * 2 + rowin) * 18 + col;
    int abase[4], aswz[4];
    #pragma unroll
    for (int mo = 0; mo < 4; ++mo) {
        int o_l = wave_o * 128 + mo * 32 + lane31;
        abase[mo] = o_l << 7;
        aswz[mo] = o_l & 7;
    }

    f32x16 zv;
    #pragma unroll
    for (int r = 0; r < 16; ++r) zv[r] = 0.f;
    f32x16 acc[4][2];
    #pragma unroll
    for (int mo = 0; mo < 4; ++mo)
        #pragma unroll
        for (int n = 0; n < 2; ++n) acc[mo][n] = zv;

    #pragma unroll 1
    for (int qt = 0; qt < 4; ++qt) {
        const char* xbuf = smem + ((qt & 1) ? XSZ : 0);
        #pragma unroll 1
        for (int k = 0; k < 9; ++k) {
            const int sl = qt * 9 + k;
            // per-wave counted waits (W=4 ops, X=6 ops):
            if (qt == 0 && k <= 1)                   asm volatile("s_waitcnt vmcnt(6)"  ::: "memory");
            else if ((qt == 1 || qt == 2) && k <= 1) asm volatile("s_waitcnt vmcnt(10)" ::: "memory");
            else if (sl == 35)                       asm volatile("s_waitcnt vmcnt(0)"  ::: "memory");
            else                                     asm volatile("s_waitcnt vmcnt(4)"  ::: "memory");
            __builtin_amdgcn_sched_barrier(0);
            __builtin_amdgcn_s_barrier();

            const int dy = (k * 11) >> 5;
            const int dx = k - dy * 3;
            const int doff = dy * 18 + dx;
            const char* wbuf = smem + WOFF + ((sl & 1) ? WSL : 0);
            const unsigned mk = mbits >> (k * 2);

            int sx[2];
            #pragma unroll
            for (int n = 0; n < 2; ++n) sx[n] = sB[n] + doff;

            __builtin_amdgcn_s_setprio(1);
            #pragma unroll
            for (int ks = 0; ks < 4; ++ks) {
                const int ua = ks * 2 + khalf;
                bf16x8 av[4];
                #pragma unroll
                for (int mo = 0; mo < 4; ++mo)
                    av[mo] = *(const bf16x8*)(wbuf + abase[mo] + ((ua ^ aswz[mo]) << 4));
                bf16x8 bv[2];
                #pragma unroll
                for (int n = 0; n < 2; ++n) {
                    i32x4 braw = *(const i32x4*)(xbuf + sx[n] * 128 + ((ua ^ (sx[n] & 7)) << 4));
                    const int mm = -(int)((mk >> n) & 1u);
                    #pragma unroll
                    for (int w4 = 0; w4 < 4; ++w4) braw[w4] &= mm;   // binary mask, exact
                    bv[n] = __builtin_bit_cast(bf16x8, braw);
                }
                #pragma unroll
                for (int mo = 0; mo < 4; ++mo)
                    #pragma unroll
                    for (int n = 0; n < 2; ++n)
                        acc[mo][n] = __builtin_amdgcn_mfma_f32_32x32x16_bf16(av[mo], bv[n], acc[mo][n], 0, 0, 0);
            }
            __builtin_amdgcn_s_setprio(0);

            asm volatile("" ::: "memory");
            __builtin_amdgcn_s_barrier();
            if (sl + 2 < 36)
                stage_w(wb, smem, WOFF + ((sl & 1) ? WSL : 0), sl + 2, wid, l);
            if (k == 8 && qt < 2)
                stage_x(hi_in, zb, smem, (qt & 1) ? XSZ : 0, b, tr, tc, qt + 2, wid, l);
        }
    }

    // ---- epilogue: LDS transpose in two 128-KB phases (rows 0-7, then 8-15).
    // Write: delta f32 at [pl][ch], 16-B units XOR-swizzled by (pl&7) -> all-bank-busy.
    // Read: lane = ch-unit, wave = pixel -> 8-B/lane coalesced global RMW.
    __syncthreads();
    #pragma unroll
    for (int ph = 0; ph < 2; ++ph) {
        if ((wave_p >> 1) == ph) {
            #pragma unroll
            for (int mo = 0; mo < 4; ++mo) {
                #pragma unroll
                for (int n = 0; n < 2; ++n) {
                    const int row_local = (wave_p & 1) * 4 + n * 2 + rowin;  // 0..7
                    const int pl = row_local * 16 + col;                      // 0..127
                    #pragma unroll
                    for (int rq = 0; rq < 4; ++rq) {
                        const int u = wave_o * 32 + mo * 8 + rq * 2 + khalf;  // ch unit
                        f32x4 v;
                        v[0] = acc[mo][n][rq * 4 + 0];
                        v[1] = acc[mo][n][rq * 4 + 1];
                        v[2] = acc[mo][n][rq * 4 + 2];
                        v[3] = acc[mo][n][rq * 4 + 3];
                        *(f32x4*)(smem + pl * 1024 + ((u ^ (pl & 7)) << 4)) = v;
                    }
                }
            }
        }
        __syncthreads();
        #pragma unroll 2
        for (int it = 0; it < 16; ++it) {
            const int pl = it * 8 + wid;                 // pl & 7 == wid
            const int h = tr * 16 + ph * 8 + (pl >> 4);
            const int w = tc * 16 + (pl & 15);
            const f32x4 d4 = *(const f32x4*)(smem + pl * 1024 + ((l ^ wid) << 4));
            const size_t base = (((size_t)((b * 128 + h) * 128 + w)) << 8) + l * 4;
            const u16x4 h4 = *(const u16x4*)(hi_in + base);
            const u16x4 l4 = *(const u16x4*)(lo_in + base);
            u16x4 ho, lo2;
            #pragma unroll
            for (int r = 0; r < 4; ++r) {
                const float xv = bf2f(h4[r]) + bf2f(l4[r]);
                const float d = d4[r];
                const float xn = xv + d / (1.f + fabsf(d));
                ho[r] = f2bf_rne(xn);
                lo2[r] = f2bf_rne(xn - bf2f(ho[r]));
            }
            *(u16x4*)(hi_out + base) = ho;
            *(u16x4*)(lo_out + base) = lo2;
        }
        if (ph == 0) __syncthreads();
    }
}

// ---- final: channel-last hi/lo shadows -> fp32 (B,C,H,W) via LDS transpose
__global__ __launch_bounds__(256)
void shadows_to_f32(const unsigned short* __restrict__ hi,
                    const unsigned short* __restrict__ lo,
                    float* __restrict__ out)
{
    __shared__ float t[64][132];
    int bid = blockIdx.x;
    const int ct = bid & 3;  bid >>= 2;
    const int h  = bid & 127; const int b = bid >> 7;
    const int tid = threadIdx.x;
    // read coalesced channel-last: 8 passes x (16 w x 64 ch)
    #pragma unroll
    for (int pass = 0; pass < 8; ++pass) {
        const int w = pass * 16 + (tid >> 4);
        const int c0 = (tid & 15) * 4;
        const size_t base = (((size_t)((b * 128 + h) * 128 + w)) << 8) + ct * 64 + c0;
        const u16x4 hv = *(const u16x4*)(hi + base);
        const u16x4 lv = *(const u16x4*)(lo + base);
        #pragma unroll
        for (int e = 0; e < 4; ++e) t[c0 + e][w] = bf2f(hv[e]) + bf2f(lv[e]);
    }
    __syncthreads();
    // write coalesced channel-major: 8 passes x (8 ch x 128 w)
    #pragma unroll
    for (int pass = 0; pass < 8; ++pass) {
        const int c = pass * 8 + (tid >> 5);
        const int w = (tid & 31) * 4;
        float4 v = make_float4(t[c][w], t[c][w + 1], t[c][w + 2], t[c][w + 3]);
        *(float4*)(out + ((size_t)(b * C_ + ct * 64 + c) * H_ + h) * W_ + w) = v;
    }
}

// ================= fp32 fallback (only if ws too small) =================
#define OT 64
#define TR 4
#define TC 16
#define CKC 16
__global__ __launch_bounds__(256)
void nca_step_f32(const float* __restrict__ xin, const float* __restrict__ wg,
                  const float* __restrict__ mask, float* __restrict__ xout)
{
    __shared__ __align__(16) float w_s[CKC][9][OT];
    __shared__ __align__(16) float x_s[CKC][TR + 2][20];
    const int tid = threadIdx.x;
    int bt = blockIdx.x;
    const int col_tile = bt & 7;  bt >>= 3;
    const int row_tile = bt & 31; bt >>= 5;
    const int ot = bt & 3;        const int b = bt >> 2;
    const int gr0 = row_tile * TR, gc0 = col_tile * TC, o_base = ot * OT;
    const int og = tid >> 4, pg = tid & 15;
    const int prow = pg >> 2, pcol4 = (pg & 3) * 4;
    const int orow = gr0 + prow, ocol0 = gc0 + pcol4;
    float mask_r[9][4];
#pragma unroll
    for (int k = 0; k < 9; ++k)
#pragma unroll
        for (int j = 0; j < 4; ++j)
            mask_r[k][j] = mask[k * NPIX + orow * W_ + (ocol0 + j)];
    float acc[4][4];
#pragma unroll
    for (int a = 0; a < 4; ++a)
#pragma unroll
        for (int j = 0; j < 4; ++j) acc[a][j] = 0.f;
    for (int chunk = 0; chunk < C_ / CKC; ++chunk) {
        const int c0 = chunk * CKC;
#pragma unroll
        for (int i = 0; i < 36; ++i) {
            const int flat = i * 256 + tid;
            const int o_l = flat / 144;
            const int r = flat - o_l * 144;
            const int c_l = r / 9;
            const int kk = r - c_l * 9;
            w_s[c_l][kk][o_l] = wg[(o_base + o_l) * (C_ * 9) + (c0 + c_l) * 9 + kk];
        }
#pragma unroll
        for (int i = 0; i < 7; ++i) {
            const int flat = i * 256 + tid;
            if (flat < CKC * 108) {
                const int c_l = flat / 108;
                const int r = flat - c_l * 108;
                const int row = r / 18, colx = r - row * 18;
                const int grow = gr0 - 1 + row, gcol = gc0 - 1 + colx;
                float v = 0.f;
                if ((unsigned)grow < (unsigned)H_ && (unsigned)gcol < (unsigned)W_)
                    v = xin[((b * C_ + c0 + c_l) * H_ + grow) * W_ + gcol];
                x_s[c_l][row][colx] = v;
            }
        }
        __syncthreads();
#pragma unroll
        for (int dyy = 0; dyy < 3; ++dyy) {
            float acck[3][4][4];
#pragma unroll
            for (int dxx = 0; dxx < 3; ++dxx)
#pragma unroll
                for (int a = 0; a < 4; ++a)
#pragma unroll
                    for (int j = 0; j < 4; ++j) acck[dxx][a][j] = 0.f;
#pragma unroll 4
            for (int c = 0; c < CKC; ++c) {
                const float4 xv4 = *(const float4*)&x_s[c][prow + dyy][pcol4];
                const float2 xv2 = *(const float2*)&x_s[c][prow + dyy][pcol4 + 4];
                const float xv[6] = {xv4.x, xv4.y, xv4.z, xv4.w, xv2.x, xv2.y};
#pragma unroll
                for (int dxx = 0; dxx < 3; ++dxx) {
                    const float4 wv = *(const float4*)&w_s[c][dyy * 3 + dxx][og * 4];
                    const float wa[4] = {wv.x, wv.y, wv.z, wv.w};
#pragma unroll
                    for (int a = 0; a < 4; ++a)
#pragma unroll
                        for (int j = 0; j < 4; ++j)
                            acck[dxx][a][j] = fmaf(wa[a], xv[j + dxx], acck[dxx][a][j]);
                }
            }
#pragma unroll
            for (int dxx = 0; dxx < 3; ++dxx) {
                const int k = dyy * 3 + dxx;
#pragma unroll
                for (int a = 0; a < 4; ++a)
#pragma unroll
                    for (int j = 0; j < 4; ++j)
                        acc[a][j] = fmaf(mask_r[k][j], acck[dxx][a][j], acc[a][j]);
            }
        }
        __syncthreads();
    }
#pragma unroll
    for (int a = 0; a < 4; ++a) {
        const int o = o_base + og * 4 + a;
#pragma unroll
        for (int j = 0; j < 4; ++j) {
            const int idx = ((b * C_ + o) * H_ + orow) * W_ + (ocol0 + j);
            const float d = acc[a][j];
            xout[idx] = xin[idx] + d / (1.0f + fabsf(d));
        }
    }
}

extern "C" void kernel_launch(void* const* d_in, const int* in_sizes, int n_in,
                              void* d_out, int out_size, void* d_ws, size_t ws_size,
                              hipStream_t stream) {
    const float* retina = (const float*)d_in[0];
    const float* wg     = (const float*)d_in[1];
    const float* mask   = (const float*)d_in[2];
    float* out = (float*)d_out;

    const size_t need = 0x4200000;   // wb+zb (2M) + hiA/loA (2x32M)

    if (ws_size >= need) {
        unsigned short* wb  = (unsigned short*)d_ws;
        unsigned short* zb  = (unsigned short*)((char*)d_ws + 0x120000);
        unsigned short* hiA = (unsigned short*)((char*)d_ws + 0x200000);
        unsigned short* loA = (unsigned short*)((char*)d_ws + 0x2200000);
        unsigned short* hiB = (unsigned short*)d_out;              // first 32 MB of out
        unsigned short* loB = hiB + (size_t)B_ * NPIX * C_;        // second 32 MB

        hipFuncSetAttribute((const void*)nca_v7,
                            hipFuncAttributeMaxDynamicSharedMemorySize, LDS_TOTAL);

        prep_w<<<2305, 256, 0, stream>>>(wg, wb, zb);
        prep_split<<<4096, 256, 0, stream>>>(retina, hiB, loB);    // state starts in B (d_out)

        // B->A->B->A->B->A : final state lands in ws, then transpose into d_out
        nca_v7<<<256, 512, LDS_TOTAL, stream>>>(hiB, loB, wb, zb, mask, hiA, loA);
        nca_v7<<<256, 512, LDS_TOTAL, stream>>>(hiA, loA, wb, zb, mask, hiB, loB);
        nca_v7<<<256, 512, LDS_TOTAL, stream>>>(hiB, loB, wb, zb, mask, hiA, loA);
        nca_v7<<<256, 512, LDS_TOTAL, stream>>>(hiA, loA, wb, zb, mask, hiB, loB);
        nca_v7<<<256, 512, LDS_TOTAL, stream>>>(hiB, loB, wb, zb, mask, hiA, loA);
        shadows_to_f32<<<2048, 256, 0, stream>>>(hiA, loA, out);
    } else {
        float* ws = (float*)d_ws;
        const int nblocks = B_ * (C_ / OT) * (H_ / TR) * (W_ / TC);
        const float* src = retina;
        float* dsts[5] = {out, ws, out, ws, out};
        for (int s = 0; s < 5; ++s) {
            nca_step_f32<<<dim3(nblocks), dim3(256), 0, stream>>>(src, wg, mask, dsts[s]);
            src = dsts[s];
        }
    }
}